// Round 9
// baseline (231.539 us; speedup 1.0000x reference)
//
#include <hip/hip_runtime.h>
#include <cstdint>
#include <cstddef>

#define NB  8
#define NC  128
#define NHW 36864

// workspace layout (float offsets)
#define GOFF  0         // 131072
#define SOFF  131072    // 1024
#define TOFF  132096    // 1024
#define ROFF  133120    // 131072
#define CVOFF 264192    // 1024
#define MHOFF 265216    // 65536 floats = 131072 shorts (bf16 M' hi fragments)
#define MLOFF 330752    // 65536 floats = 131072 shorts (bf16 M' lo fragments)

typedef __attribute__((ext_vector_type(8))) short short8;
typedef __attribute__((ext_vector_type(4))) float f32x4;

static __device__ __forceinline__ f32x4 zero4(){ f32x4 v = {0.f,0.f,0.f,0.f}; return v; }

// float -> bf16 bits via native __bf16 (compiler emits v_cvt_pk_bf16_f32 pairs)
static __device__ __forceinline__ short bfbits(float f){
    union { __bf16 b; short s; } u; u.b = (__bf16)f; return u.s;
}
// hi/lo split: h = bf16(f), l = bf16(f - float(h))
static __device__ __forceinline__ void cv2(float f, short& hb, short& lb){
    union { __bf16 b; short s; } u;
    u.b = (__bf16)f; hb = u.s;
    float hf = (float)u.b;
    u.b = (__bf16)(f - hf); lb = u.s;
}
// two f32x4 (8 consecutive cols) -> hi/lo short8 fragments; returns sum
static __device__ __forceinline__ float cv8(f32x4 v0, f32x4 v1, short8& h, short8& l){
    float ss = 0.f;
#pragma unroll
    for (int j=0;j<4;j++){
        short hb, lb;
        cv2(v0[j], hb, lb); h[j]   = hb; l[j]   = lb;
        cv2(v1[j], hb, lb); h[4+j] = hb; l[4+j] = lb;
        ss += v0[j] + v1[j];
    }
    return ss;
}

// async global -> LDS, 16B per lane. lds base must be wave-uniform.
static __device__ __forceinline__ void gload16(const float* g, float* lds){
    __builtin_amdgcn_global_load_lds((const __attribute__((address_space(1))) void*)g,
                                     (__attribute__((address_space(3))) void*)lds,
                                     16, 0, 0);
}

// ---- K0: zero G and svec (atomic accumulation targets) ----
__global__ __launch_bounds__(256) void k_zero(float* __restrict__ p){
    const int i = (blockIdx.x*256 + threadIdx.x)*4;
    *(f32x4*)(p + i) = zero4();
}

// ======================= K1: Gram G = sum_n x x^T ==========================
// Counted-vmcnt pipeline (T4): every wave issues EXACTLY 5 global_load_lds per
// tile (1280-slot buffer incl. 128 dump slots, per-lane source clamped in
// range), then s_waitcnt vmcnt(5) + raw s_barrier — prefetch loads stay in
// flight across the barrier. LDS 2 x 20 KB = 40 KB -> 4 blocks/CU.
#define GR_NT 9
#define GR_TS 1152          // real 16B slots per tile (128 rows * 9)
#define GR_SLOTS 1280       // padded slots per buffer
#define GR_TF 5120          // floats per buffer

static __device__ __forceinline__ void gram_stage(float* Lt, const float* __restrict__ xb,
                                                  int n0, int tid){
#pragma unroll
    for (int i=0;i<5;i++){
        const int Sbase = i*256 + (tid & ~63);      // wave-uniform slot base
        const int S   = Sbase + (tid & 63);
        const int R   = S / 9;                      // row
        const int grp = S - R*9;                    // 16B slot in row
        const int c4  = (grp == 8) ? 0 : grp*4;     // pad slot: dup fetch, never read
        // dump slots (S >= 1152): clamp source in-range; data never read
        const float* src = (S < GR_TS) ? (xb + (size_t)R*NHW + n0 + c4) : xb;
        gload16(src, Lt + (size_t)Sbase*4);
    }
}

template<int W>
static __device__ __forceinline__ void gram_work(const float* __restrict__ xb,
        float* __restrict__ Gb, float* __restrict__ sb,
        float* Ls, const int chunk, const int tid){
    const int lane = tid & 63;
    const int l16 = lane & 15, lgi = lane >> 4;
    constexpr int W2 = 2*W;

    f32x4 acc[2][8];
#pragma unroll
    for (int p=0;p<2;p++)
#pragma unroll
      for (int g=0;g<8;g++) acc[p][g] = zero4();
    float ssum[8];
#pragma unroll
    for (int g=0;g<8;g++) ssum[g] = 0.f;

    const int nb = chunk*288;
    gram_stage(Ls, xb, nb, tid);                    // tile 0 -> buf0 (5 loads out)

    for (int t=0; t<GR_NT; ++t){
        if (t+1 < GR_NT){
            gram_stage(Ls + ((t+1)&1)*GR_TF, xb, nb + (t+1)*32, tid);  // 10 out
            asm volatile("s_waitcnt vmcnt(5)" ::: "memory");           // t landed
        } else {
            asm volatile("s_waitcnt vmcnt(0)" ::: "memory");
        }
        __builtin_amdgcn_sched_barrier(0);
        __builtin_amdgcn_s_barrier();               // all waves: tile t in LDS

        const float* Lb = Ls + (t&1)*GR_TF;
        // A-fragments: rows W2*16.., (W2+1)*16.. (also reused as B rows g=W2,W2+1)
        f32x4 a00 = *(const f32x4*)(Lb + (size_t)(W2*16     + l16)*36 + lgi*8);
        f32x4 a01 = *(const f32x4*)(Lb + (size_t)(W2*16     + l16)*36 + lgi*8 + 4);
        f32x4 a10 = *(const f32x4*)(Lb + (size_t)((W2+1)*16 + l16)*36 + lgi*8);
        f32x4 a11 = *(const f32x4*)(Lb + (size_t)((W2+1)*16 + l16)*36 + lgi*8 + 4);
        short8 hA0, lA0, hA1, lA1;
        const float sA0 = cv8(a00, a01, hA0, lA0);
        const float sA1 = cv8(a10, a11, hA1, lA1);

#pragma unroll
        for (int g=0; g<8; g++){
            short8 hg, lg2;
            float sg;
            if (g == W2)        { hg = hA0; lg2 = lA0; sg = sA0; }
            else if (g == W2+1) { hg = hA1; lg2 = lA1; sg = sA1; }
            else {
                f32x4 b0 = *(const f32x4*)(Lb + (size_t)(g*16 + l16)*36 + lgi*8);
                f32x4 b1 = *(const f32x4*)(Lb + (size_t)(g*16 + l16)*36 + lgi*8 + 4);
                sg = cv8(b0, b1, hg, lg2);
            }
            if (W == 0) ssum[g] += sg;
            acc[0][g] = __builtin_amdgcn_mfma_f32_16x16x32_bf16(hA0, hg,  acc[0][g], 0,0,0);
            acc[0][g] = __builtin_amdgcn_mfma_f32_16x16x32_bf16(hA0, lg2, acc[0][g], 0,0,0);
            acc[0][g] = __builtin_amdgcn_mfma_f32_16x16x32_bf16(lA0, hg,  acc[0][g], 0,0,0);
            acc[1][g] = __builtin_amdgcn_mfma_f32_16x16x32_bf16(hA1, hg,  acc[1][g], 0,0,0);
            acc[1][g] = __builtin_amdgcn_mfma_f32_16x16x32_bf16(hA1, lg2, acc[1][g], 0,0,0);
            acc[1][g] = __builtin_amdgcn_mfma_f32_16x16x32_bf16(lA1, hg,  acc[1][g], 0,0,0);
        }
        __builtin_amdgcn_s_barrier();   // protect buf (t&1) from next-iter stage
    }

    // C/D layout (pass-verified): col = lane&15, row = (lane>>4)*4 + reg
#pragma unroll
    for (int p=0;p<2;p++){
        const int rg = W2 + p;
#pragma unroll
        for (int g=0;g<8;g++){
#pragma unroll
            for (int r=0;r<4;r++){
                atomicAdd(&Gb[(size_t)(rg*16 + lgi*4 + r)*NC + g*16 + l16], acc[p][g][r]);
            }
        }
    }
    if (W == 0){
#pragma unroll
        for (int g=0;g<8;g++){
            float v = ssum[g];
            v += __shfl_xor(v, 16);
            v += __shfl_xor(v, 32);
            if (lane < 16) atomicAdd(&sb[g*16 + lane], v);
        }
    }
}

__global__ __launch_bounds__(256, 4) void k_gram(const float* __restrict__ x,
                                                 float* __restrict__ G,
                                                 float* __restrict__ svec){
    __shared__ float Ls[2*GR_TF];   // 40 KB
    const int b     = blockIdx.y;
    const int chunk = blockIdx.x;   // 128 chunks * 288 n
    const int tid   = threadIdx.x;
    const int wid   = tid >> 6;
    const float* xb = x + (size_t)b*NC*NHW;
    float* Gb = G + (size_t)b*NC*NC;
    float* sb = svec + b*NC;
    switch (wid){
        case 0: gram_work<0>(xb, Gb, sb, Ls, chunk, tid); break;
        case 1: gram_work<1>(xb, Gb, sb, Ls, chunk, tid); break;
        case 2: gram_work<2>(xb, Gb, sb, Ls, chunk, tid); break;
        default: gram_work<3>(xb, Gb, sb, Ls, chunk, tid); break;
    }
}

// ---- K2: energy = Wq G Wk^T + rank-1 terms; softmax -> A (LDS); t = A bv; R = A Wv ----
// (round-6/7 verbatim, PASSING)
__global__ __launch_bounds__(256) void k_energyav(const float* __restrict__ G,
        const float* __restrict__ svec,
        const float* __restrict__ Wq, const float* __restrict__ bq,
        const float* __restrict__ Wk, const float* __restrict__ bk,
        const float* __restrict__ bv, const float* __restrict__ Wv,
        float* __restrict__ R, float* __restrict__ tvec){
    const int b  = blockIdx.y;
    const int d0 = blockIdx.x * 16;
    const int tid = threadIdx.x;
    const int d  = tid & 15;
    const int ec = tid >> 4;

    __shared__ float Ps[16][128];
    __shared__ float Es[16][128];
    __shared__ float red[16][16];
    __shared__ float rowmax[16];
    __shared__ float rowsum[16];
    __shared__ float qs[16];

    const float* Wqrow = Wq + (size_t)(d0 + d)*NC;
    const float* sb = svec + b*NC;
#pragma unroll
    for (int i=0;i<8;i++){
        const int c = ec*8 + i;
        const float* Grow = G + ((size_t)b*NC + c)*NC;
        float a = 0.f;
        for (int c4=0;c4<32;c4++){
            f32x4 g4 = *(const f32x4*)(Grow + c4*4);
            f32x4 w4 = *(const f32x4*)(Wqrow + c4*4);
            a += g4[0]*w4[0] + g4[1]*w4[1] + g4[2]*w4[2] + g4[3]*w4[3];
        }
        Ps[d][c] = a;
    }
    if (ec == 0){
        float a = 0.f;
        for (int c4=0;c4<32;c4++){
            f32x4 w4 = *(const f32x4*)(Wqrow + c4*4);
            f32x4 s4 = *(const f32x4*)(sb + c4*4);
            a += w4[0]*s4[0] + w4[1]*s4[1] + w4[2]*s4[2] + w4[3]*s4[3];
        }
        qs[d] = a;
    }
    __syncthreads();
    const float bqd = bq[d0+d];
#pragma unroll
    for (int i=0;i<8;i++){
        const int e = ec*8 + i;
        const float* Wkrow = Wk + (size_t)e*NC;
        float ea = 0.f, ks = 0.f;
        for (int c4=0;c4<32;c4++){
            f32x4 w4 = *(const f32x4*)(Wkrow + c4*4);
            f32x4 p4 = *(const f32x4*)(&Ps[d][c4*4]);
            f32x4 s4 = *(const f32x4*)(sb + c4*4);
            ea += w4[0]*p4[0]+w4[1]*p4[1]+w4[2]*p4[2]+w4[3]*p4[3];
            ks += w4[0]*s4[0]+w4[1]*s4[1]+w4[2]*s4[2]+w4[3]*s4[3];
        }
        const float bke = bk[e];
        Es[d][e] = ea + bke*qs[d] + bqd*ks + (float)NHW*bqd*bke;
    }
    float m8 = -3.4e38f;
#pragma unroll
    for (int i=0;i<8;i++) m8 = fmaxf(m8, Es[d][ec*8+i]);
    red[d][ec] = m8;
    __syncthreads();
    if (tid < 16){
        float m = red[tid][0];
        for (int j=1;j<16;j++) m = fmaxf(m, red[tid][j]);
        rowmax[tid] = m;
    }
    __syncthreads();
    const float rm = rowmax[d];
    float s8 = 0.f;
#pragma unroll
    for (int i=0;i<8;i++){
        float ex = expf(Es[d][ec*8+i] - rm);
        Es[d][ec*8+i] = ex;
        s8 += ex;
    }
    red[d][ec] = s8;
    __syncthreads();
    if (tid < 16){
        float sm = 0.f;
        for (int j=0;j<16;j++) sm += red[tid][j];
        rowsum[tid] = sm;
    }
    __syncthreads();
    const float inv = 1.f / rowsum[d];
    float ta = 0.f;
#pragma unroll
    for (int i=0;i<8;i++){
        const int e = ec*8 + i;
        float av = Es[d][e] * inv;
        Es[d][e] = av;
        ta += av * bv[e];
    }
    red[d][ec] = ta;
    __syncthreads();
    if (tid < 16){
        float sm = 0.f;
        for (int j=0;j<16;j++) sm += red[tid][j];
        tvec[b*NC + d0 + tid] = sm;
    }
    const int c0 = ec*8;
    float racc[8];
#pragma unroll
    for (int i=0;i<8;i++) racc[i]=0.f;
    for (int e=0;e<NC;e++){
        const float av = Es[d][e];
        const float* wv = Wv + (size_t)e*NC + c0;
        f32x4 w0 = *(const f32x4*)wv;
        f32x4 w1 = *(const f32x4*)(wv+4);
        racc[0]+=av*w0[0]; racc[1]+=av*w0[1]; racc[2]+=av*w0[2]; racc[3]+=av*w0[3];
        racc[4]+=av*w1[0]; racc[5]+=av*w1[1]; racc[6]+=av*w1[2]; racc[7]+=av*w1[3];
    }
    float* Rrow = R + ((size_t)b*NC + d0 + d)*NC + c0;
#pragma unroll
    for (int i=0;i<8;i++) Rrow[i] = racc[i];
}

// ---- K3: M' = gamma*Wo*R + I -> hi/lo bf16 B-fragments; cvg = gamma*(Wo t + bo) ----
// (round-7 verbatim, PASSING)
__global__ __launch_bounds__(256) void k_om(const float* __restrict__ R,
        const float* __restrict__ Wo, const float* __restrict__ bo,
        const float* __restrict__ tvec, const float* __restrict__ gamma,
        short* __restrict__ Mh_, short* __restrict__ Ml_, float* __restrict__ cvg){
    const int b = blockIdx.y, o0 = blockIdx.x*16;
    const int tid = threadIdx.x, o = tid&15, cc = tid>>4;
    const int c0 = cc*8;                      // cin octet base
    const float* Worow = Wo + (size_t)(o0+o)*NC;
    const float* tb = tvec + b*NC;
    float a[8];
#pragma unroll
    for (int i=0;i<8;i++) a[i]=0.f;
    float cv = 0.f;
    for (int dd=0; dd<NC; dd++){
        const float wv = Worow[dd];
        const float* r = R + ((size_t)b*NC + dd)*NC + c0;
        f32x4 r0 = *(const f32x4*)r;
        f32x4 r1 = *(const f32x4*)(r+4);
        a[0]+=wv*r0[0]; a[1]+=wv*r0[1]; a[2]+=wv*r0[2]; a[3]+=wv*r0[3];
        a[4]+=wv*r1[0]; a[5]+=wv*r1[1]; a[6]+=wv*r1[2]; a[7]+=wv*r1[3];
        cv += wv*tb[dd];
    }
    const float gm = gamma[0];
    const int c   = o0 + o;
    const int cg  = c >> 4;
    const int kst = cc >> 2, lgv = cc & 3;
    const size_t idx = ((((size_t)b*8 + cg)*4 + kst)*64 + (lgv*16 + (c & 15)))*8;
    short8 hh, ll;
#pragma unroll
    for (int i=0;i<8;i++){
        float val = gm*a[i] + ((c0 + i) == c ? 1.f : 0.f);   // M' = gm*M + I
        short hb, lb; cv2(val, hb, lb);
        hh[i]=hb; ll[i]=lb;
    }
    *(short8*)(Mh_ + idx) = hh;
    *(short8*)(Ml_ + idx) = ll;
    if (cc == 0) cvg[b*NC + c] = gm*(cv + bo[c]);
}

// ---- K4: out = M' x + cvg  (A = x from swizzled Xt; B = M' hi/lo) ----
// Round-7 structure; changes: store loops reordered (cg outer, t inner) so each
// c-row's two 64B halves of a 128B line are written back-to-back; VGPR capped
// via __launch_bounds__(256,4).
__global__ __launch_bounds__(256, 4) void k_final(const float* __restrict__ x,
        const short* __restrict__ Mh_, const short* __restrict__ Ml_,
        const float* __restrict__ cvg, float* __restrict__ out){
    __shared__ short Xt[NC*128];   // 32 KB: row n (local), 16 slots of 8 shorts
    const int b   = blockIdx.y;
    const int n0  = blockIdx.x * 128;
    const int tid = threadIdx.x;
    const int wid = tid >> 6, lane = tid & 63;
    const int l16 = lane & 15, lgi = lane >> 4;

    // ---- stage (round-6 verbatim): thread (nr = tid&31, mb8 = tid>>5), 2 reps
    const int nr = tid & 31, mb8 = tid >> 5;
    const float* xs = x + (size_t)b*NC*NHW + n0 + nr*4;
#pragma unroll
    for (int rep=0; rep<2; rep++){
        const int m0 = rep*64 + mb8*8;
        const float* xm = xs + (size_t)m0*NHW;
        f32x4 v0 = *(const f32x4*)(xm);
        f32x4 v1 = *(const f32x4*)(xm + (size_t)1*NHW);
        f32x4 v2 = *(const f32x4*)(xm + (size_t)2*NHW);
        f32x4 v3 = *(const f32x4*)(xm + (size_t)3*NHW);
        f32x4 v4 = *(const f32x4*)(xm + (size_t)4*NHW);
        f32x4 v5 = *(const f32x4*)(xm + (size_t)5*NHW);
        f32x4 v6 = *(const f32x4*)(xm + (size_t)6*NHW);
        f32x4 v7 = *(const f32x4*)(xm + (size_t)7*NHW);
#pragma unroll
        for (int r=0;r<4;r++){
            short8 w;
            w[0]=bfbits(v0[r]); w[1]=bfbits(v1[r]); w[2]=bfbits(v2[r]); w[3]=bfbits(v3[r]);
            w[4]=bfbits(v4[r]); w[5]=bfbits(v5[r]); w[6]=bfbits(v6[r]); w[7]=bfbits(v7[r]);
            const int n = nr*4 + r;
            const int slot = (rep*8 + mb8) ^ ((n>>2)&15) ^ ((n&3)<<2);
            *(short8*)(&Xt[n*128 + slot*8]) = w;
        }
    }
    __syncthreads();

    f32x4 acc[2][8];   // [n 16-block t][cg]
#pragma unroll
    for (int t=0;t<2;t++)
#pragma unroll
      for (int g=0;g<8;g++) acc[t][g]=zero4();

    const short* Mh = Mh_ + (size_t)b*16384;
    const short* Ml = Ml_ + (size_t)b*16384;

#pragma unroll
    for (int ks=0; ks<4; ks++){
        const int nA0 = wid*32 + l16;
        const int nA1 = nA0 + 16;
        const int sl  = ks*4 + lgi;
        const int s0  = sl ^ ((nA0>>2)&15) ^ ((nA0&3)<<2);
        const int s1  = sl ^ ((nA1>>2)&15) ^ ((nA1&3)<<2);
        short8 a0 = *(const short8*)(&Xt[nA0*128 + s0*8]);
        short8 a1 = *(const short8*)(&Xt[nA1*128 + s1*8]);
#pragma unroll
        for (int cg=0; cg<8; cg++){
            const size_t bi = (((size_t)cg*4 + ks)*64 + lane)*8;
            short8 bh = *(const short8*)(Mh + bi);
            short8 bl = *(const short8*)(Ml + bi);
            acc[0][cg] = __builtin_amdgcn_mfma_f32_16x16x32_bf16(a0, bh, acc[0][cg], 0,0,0);
            acc[0][cg] = __builtin_amdgcn_mfma_f32_16x16x32_bf16(a0, bl, acc[0][cg], 0,0,0);
            acc[1][cg] = __builtin_amdgcn_mfma_f32_16x16x32_bf16(a1, bh, acc[1][cg], 0,0,0);
            acc[1][cg] = __builtin_amdgcn_mfma_f32_16x16x32_bf16(a1, bl, acc[1][cg], 0,0,0);
        }
    }

    // C/D: row(i)=n-offset=(lane>>4)*4+r, col(j)=c=cg*16+(lane&15)
    // t inner: per c the two 64B halves of the 128B line store back-to-back.
    const float* cb = cvg + b*NC;
#pragma unroll
    for (int cg=0;cg<8;cg++){
        const int c = cg*16 + l16;
        const float ccv = cb[c];
        float* orow = &out[((size_t)b*NC + c)*NHW + n0 + wid*32 + lgi*4];
#pragma unroll
        for (int t=0;t<2;t++){
            f32x4 o = acc[t][cg];
            o[0]+=ccv; o[1]+=ccv; o[2]+=ccv; o[3]+=ccv;
            *(f32x4*)(orow + t*16) = o;
        }
    }
}

extern "C" void kernel_launch(void* const* d_in, const int* in_sizes, int n_in,
                              void* d_out, int out_size, void* d_ws, size_t ws_size,
                              hipStream_t stream){
    const float* x     = (const float*)d_in[0];
    const float* Wq    = (const float*)d_in[1];
    const float* bq    = (const float*)d_in[2];
    const float* Wk    = (const float*)d_in[3];
    const float* bk    = (const float*)d_in[4];
    const float* Wv    = (const float*)d_in[5];
    const float* bv    = (const float*)d_in[6];
    const float* Wo    = (const float*)d_in[7];
    const float* bo    = (const float*)d_in[8];
    const float* gamma = (const float*)d_in[9];
    float* out = (float*)d_out;

    float* w  = (float*)d_ws;
    float* G  = w + GOFF;
    float* S  = w + SOFF;
    float* T  = w + TOFF;
    float* R  = w + ROFF;
    float* CV = w + CVOFF;
    short* Mh = (short*)(w + MHOFF);
    short* Ml = (short*)(w + MLOFF);

    // zero atomic-accumulation targets (G: 131072 + svec: 1024 floats)
    k_zero    <<<dim3(129),     256, 0, stream>>>(G);

    k_gram    <<<dim3(128, NB), 256, 0, stream>>>(x, G, S);
    k_energyav<<<dim3(8,   NB), 256, 0, stream>>>(G, S, Wq, bq, Wk, bk, bv, Wv, R, T);
    k_om      <<<dim3(8,   NB), 256, 0, stream>>>(R, Wo, bo, T, gamma, Mh, Ml, CV);
    k_final   <<<dim3(288, NB), 256, 0, stream>>>(x, Mh, Ml, CV, out);
}

// Round 11
// 226.891 us; speedup vs baseline: 1.0205x; 1.0205x over previous
//
#include <hip/hip_runtime.h>
#include <cstdint>
#include <cstddef>

#define NB  8
#define NC  128
#define NHW 36864

// workspace layout (float offsets)
#define GOFF  0         // 131072
#define SOFF  131072    // 1024
#define TOFF  132096    // 1024
#define ROFF  133120    // 131072
#define CVOFF 264192    // 1024
#define MHOFF 265216    // 65536 floats = 131072 shorts (bf16 M' hi fragments)
#define MLOFF 330752    // 65536 floats = 131072 shorts (bf16 M' lo fragments)

typedef __attribute__((ext_vector_type(8))) short short8;
typedef __attribute__((ext_vector_type(4))) float f32x4;

static __device__ __forceinline__ f32x4 zero4(){ f32x4 v = {0.f,0.f,0.f,0.f}; return v; }

// float -> bf16 bits via native __bf16 (compiler emits v_cvt_pk_bf16_f32 pairs)
static __device__ __forceinline__ short bfbits(float f){
    union { __bf16 b; short s; } u; u.b = (__bf16)f; return u.s;
}
// hi/lo split: h = bf16(f), l = bf16(f - float(h))
static __device__ __forceinline__ void cv2(float f, short& hb, short& lb){
    union { __bf16 b; short s; } u;
    u.b = (__bf16)f; hb = u.s;
    float hf = (float)u.b;
    u.b = (__bf16)(f - hf); lb = u.s;
}
// two f32x4 (8 consecutive cols) -> hi/lo short8 fragments; returns sum
static __device__ __forceinline__ float cv8(f32x4 v0, f32x4 v1, short8& h, short8& l){
    float ss = 0.f;
#pragma unroll
    for (int j=0;j<4;j++){
        short hb, lb;
        cv2(v0[j], hb, lb); h[j]   = hb; l[j]   = lb;
        cv2(v1[j], hb, lb); h[4+j] = hb; l[4+j] = lb;
        ss += v0[j] + v1[j];
    }
    return ss;
}

// ---- K0: zero G and svec (atomic accumulation targets) ----
__global__ __launch_bounds__(256) void k_zero(float* __restrict__ p){
    const int i = (blockIdx.x*256 + threadIdx.x)*4;
    *(f32x4*)(p + i) = zero4();
}

// ======================= K1: Gram G = sum_n x x^T ==========================
// Convert-ONCE bf16 staging: each thread loads 16 f32, converts to hi/lo bf16,
// ds_write_b128 into [row][col] tiles with row stride 40 shorts (80 B:
// 16B-aligned; bank starts {0,4,..,28}x2 -> 2-way = free). Fragments become
// single ds_read_b128 of MFMA-ready bf16. T14: next-tile loads issued before
// compute, convert+write after. One barrier per tile. G numerics identical.
#define GNT 9           // 9 tiles * 32 n = 288 n per chunk
#define GLDH 5120       // shorts per (buf,half): 128*40

__global__ __launch_bounds__(256) void k_gram(const float* __restrict__ x,
                                              float* __restrict__ G,
                                              float* __restrict__ svec){
    __shared__ short Ls[2][2][GLDH];   // [buf][hi/lo][row*40+col] : 40 KB
    const int b     = blockIdx.y;
    const int chunk = blockIdx.x;      // 128 chunks * 288 n
    const int tid   = threadIdx.x;
    const int wid   = tid >> 6, lane = tid & 63;
    const int l16   = lane & 15, lgi = lane >> 4;
    const int sr    = tid >> 1;          // staging row (0..127)
    const int sh    = (tid & 1) * 16;    // staging col-half (0|16)

    const float* xs = x + (size_t)b*NC*NHW + (size_t)sr*NHW + chunk*288 + sh;

    float srow = 0.f;
    f32x4 acc[2][8];
#pragma unroll
    for (int p=0;p<2;p++)
#pragma unroll
      for (int g=0;g<8;g++) acc[p][g] = zero4();

    // prologue: stage tile 0 into buf 0
    {
        f32x4 v0 = *(const f32x4*)(xs);
        f32x4 v1 = *(const f32x4*)(xs+4);
        f32x4 v2 = *(const f32x4*)(xs+8);
        f32x4 v3 = *(const f32x4*)(xs+12);
        short8 h0,l0,h1,l1;
        srow += cv8(v0,v1,h0,l0) + cv8(v2,v3,h1,l1);
        short* dh = &Ls[0][0][sr*40 + sh];
        short* dl = &Ls[0][1][sr*40 + sh];
        *(short8*)dh = h0; *(short8*)(dh+8) = h1;
        *(short8*)dl = l0; *(short8*)(dl+8) = l1;
    }
    __syncthreads();

    for (int t=0; t<GNT; ++t){
        f32x4 v0,v1,v2,v3;
        const bool pf = (t+1 < GNT);
        if (pf){                            // issue next-tile loads EARLY (T14)
            const float* p = xs + (t+1)*32;
            v0 = *(const f32x4*)(p);   v1 = *(const f32x4*)(p+4);
            v2 = *(const f32x4*)(p+8); v3 = *(const f32x4*)(p+12);
        }
        {   // compute on buf t&1
            const short* Lh = Ls[t&1][0];
            const short* Ll = Ls[t&1][1];
            const int ra0 = (wid*32      + l16)*40 + lgi*8;
            const int ra1 = (wid*32 + 16 + l16)*40 + lgi*8;
            short8 hA0 = *(const short8*)(Lh + ra0);
            short8 lA0 = *(const short8*)(Ll + ra0);
            short8 hA1 = *(const short8*)(Lh + ra1);
            short8 lA1 = *(const short8*)(Ll + ra1);
#pragma unroll
            for (int g=0; g<8; g++){
                const int rb = (g*16 + l16)*40 + lgi*8;
                short8 hg  = *(const short8*)(Lh + rb);
                short8 lg2 = *(const short8*)(Ll + rb);
                acc[0][g] = __builtin_amdgcn_mfma_f32_16x16x32_bf16(hA0, hg,  acc[0][g], 0,0,0);
                acc[0][g] = __builtin_amdgcn_mfma_f32_16x16x32_bf16(hA0, lg2, acc[0][g], 0,0,0);
                acc[0][g] = __builtin_amdgcn_mfma_f32_16x16x32_bf16(lA0, hg,  acc[0][g], 0,0,0);
                acc[1][g] = __builtin_amdgcn_mfma_f32_16x16x32_bf16(hA1, hg,  acc[1][g], 0,0,0);
                acc[1][g] = __builtin_amdgcn_mfma_f32_16x16x32_bf16(hA1, lg2, acc[1][g], 0,0,0);
                acc[1][g] = __builtin_amdgcn_mfma_f32_16x16x32_bf16(lA1, hg,  acc[1][g], 0,0,0);
            }
        }
        if (pf){                            // convert + write LATE (other buf)
            short8 h0,l0,h1,l1;
            srow += cv8(v0,v1,h0,l0) + cv8(v2,v3,h1,l1);
            short* dh = &Ls[(t+1)&1][0][sr*40 + sh];
            short* dl = &Ls[(t+1)&1][1][sr*40 + sh];
            *(short8*)dh = h0; *(short8*)(dh+8) = h1;
            *(short8*)dl = l0; *(short8*)(dl+8) = l1;
        }
        __syncthreads();
    }

    // C/D layout (pass-verified): col = lane&15, row = (lane>>4)*4 + reg
    float* Gb = G + (size_t)b*NC*NC;
#pragma unroll
    for (int p=0;p<2;p++){
        const int rg = wid*2 + p;
#pragma unroll
        for (int g=0;g<8;g++){
#pragma unroll
            for (int r=0;r<4;r++){
                atomicAdd(&Gb[(size_t)(rg*16 + lgi*4 + r)*NC + g*16 + l16], acc[p][g][r]);
            }
        }
    }
    srow += __shfl_xor(srow, 1);
    if ((tid & 1) == 0) atomicAdd(&svec[b*NC + sr], srow);
}

// ---- K2: energy = Wq G Wk^T + rank-1 terms; softmax -> A (LDS); t = A bv; R = A Wv ----
// (round-9 verbatim, PASSING)
__global__ __launch_bounds__(256) void k_energyav(const float* __restrict__ G,
        const float* __restrict__ svec,
        const float* __restrict__ Wq, const float* __restrict__ bq,
        const float* __restrict__ Wk, const float* __restrict__ bk,
        const float* __restrict__ bv, const float* __restrict__ Wv,
        float* __restrict__ R, float* __restrict__ tvec){
    const int b  = blockIdx.y;
    const int d0 = blockIdx.x * 16;
    const int tid = threadIdx.x;
    const int d  = tid & 15;
    const int ec = tid >> 4;

    __shared__ float Ps[16][128];
    __shared__ float Es[16][128];
    __shared__ float red[16][16];
    __shared__ float rowmax[16];
    __shared__ float rowsum[16];
    __shared__ float qs[16];

    const float* Wqrow = Wq + (size_t)(d0 + d)*NC;
    const float* sb = svec + b*NC;
#pragma unroll
    for (int i=0;i<8;i++){
        const int c = ec*8 + i;
        const float* Grow = G + ((size_t)b*NC + c)*NC;
        float a = 0.f;
        for (int c4=0;c4<32;c4++){
            f32x4 g4 = *(const f32x4*)(Grow + c4*4);
            f32x4 w4 = *(const f32x4*)(Wqrow + c4*4);
            a += g4[0]*w4[0] + g4[1]*w4[1] + g4[2]*w4[2] + g4[3]*w4[3];
        }
        Ps[d][c] = a;
    }
    if (ec == 0){
        float a = 0.f;
        for (int c4=0;c4<32;c4++){
            f32x4 w4 = *(const f32x4*)(Wqrow + c4*4);
            f32x4 s4 = *(const f32x4*)(sb + c4*4);
            a += w4[0]*s4[0] + w4[1]*s4[1] + w4[2]*s4[2] + w4[3]*s4[3];
        }
        qs[d] = a;
    }
    __syncthreads();
    const float bqd = bq[d0+d];
#pragma unroll
    for (int i=0;i<8;i++){
        const int e = ec*8 + i;
        const float* Wkrow = Wk + (size_t)e*NC;
        float ea = 0.f, ks = 0.f;
        for (int c4=0;c4<32;c4++){
            f32x4 w4 = *(const f32x4*)(Wkrow + c4*4);
            f32x4 p4 = *(const f32x4*)(&Ps[d][c4*4]);
            f32x4 s4 = *(const f32x4*)(sb + c4*4);
            ea += w4[0]*p4[0]+w4[1]*p4[1]+w4[2]*p4[2]+w4[3]*p4[3];
            ks += w4[0]*s4[0]+w4[1]*s4[1]+w4[2]*s4[2]+w4[3]*s4[3];
        }
        const float bke = bk[e];
        Es[d][e] = ea + bke*qs[d] + bqd*ks + (float)NHW*bqd*bke;
    }
    float m8 = -3.4e38f;
#pragma unroll
    for (int i=0;i<8;i++) m8 = fmaxf(m8, Es[d][ec*8+i]);
    red[d][ec] = m8;
    __syncthreads();
    if (tid < 16){
        float m = red[tid][0];
        for (int j=1;j<16;j++) m = fmaxf(m, red[tid][j]);
        rowmax[tid] = m;
    }
    __syncthreads();
    const float rm = rowmax[d];
    float s8 = 0.f;
#pragma unroll
    for (int i=0;i<8;i++){
        float ex = expf(Es[d][ec*8+i] - rm);
        Es[d][ec*8+i] = ex;
        s8 += ex;
    }
    red[d][ec] = s8;
    __syncthreads();
    if (tid < 16){
        float sm = 0.f;
        for (int j=0;j<16;j++) sm += red[tid][j];
        rowsum[tid] = sm;
    }
    __syncthreads();
    const float inv = 1.f / rowsum[d];
    float ta = 0.f;
#pragma unroll
    for (int i=0;i<8;i++){
        const int e = ec*8 + i;
        float av = Es[d][e] * inv;
        Es[d][e] = av;
        ta += av * bv[e];
    }
    red[d][ec] = ta;
    __syncthreads();
    if (tid < 16){
        float sm = 0.f;
        for (int j=0;j<16;j++) sm += red[tid][j];
        tvec[b*NC + d0 + tid] = sm;
    }
    const int c0 = ec*8;
    float racc[8];
#pragma unroll
    for (int i=0;i<8;i++) racc[i]=0.f;
    for (int e=0;e<NC;e++){
        const float av = Es[d][e];
        const float* wv = Wv + (size_t)e*NC + c0;
        f32x4 w0 = *(const f32x4*)wv;
        f32x4 w1 = *(const f32x4*)(wv+4);
        racc[0]+=av*w0[0]; racc[1]+=av*w0[1]; racc[2]+=av*w0[2]; racc[3]+=av*w0[3];
        racc[4]+=av*w1[0]; racc[5]+=av*w1[1]; racc[6]+=av*w1[2]; racc[7]+=av*w1[3];
    }
    float* Rrow = R + ((size_t)b*NC + d0 + d)*NC + c0;
#pragma unroll
    for (int i=0;i<8;i++) Rrow[i] = racc[i];
}

// ---- K3: M' = gamma*Wo*R + I -> hi/lo bf16 B-fragments; cvg = gamma*(Wo t + bo) ----
// (round-9 verbatim, PASSING)
__global__ __launch_bounds__(256) void k_om(const float* __restrict__ R,
        const float* __restrict__ Wo, const float* __restrict__ bo,
        const float* __restrict__ tvec, const float* __restrict__ gamma,
        short* __restrict__ Mh_, short* __restrict__ Ml_, float* __restrict__ cvg){
    const int b = blockIdx.y, o0 = blockIdx.x*16;
    const int tid = threadIdx.x, o = tid&15, cc = tid>>4;
    const int c0 = cc*8;                      // cin octet base
    const float* Worow = Wo + (size_t)(o0+o)*NC;
    const float* tb = tvec + b*NC;
    float a[8];
#pragma unroll
    for (int i=0;i<8;i++) a[i]=0.f;
    float cv = 0.f;
    for (int dd=0; dd<NC; dd++){
        const float wv = Worow[dd];
        const float* r = R + ((size_t)b*NC + dd)*NC + c0;
        f32x4 r0 = *(const f32x4*)r;
        f32x4 r1 = *(const f32x4*)(r+4);
        a[0]+=wv*r0[0]; a[1]+=wv*r0[1]; a[2]+=wv*r0[2]; a[3]+=wv*r0[3];
        a[4]+=wv*r1[0]; a[5]+=wv*r1[1]; a[6]+=wv*r1[2]; a[7]+=wv*r1[3];
        cv += wv*tb[dd];
    }
    const float gm = gamma[0];
    const int c   = o0 + o;
    const int cg  = c >> 4;
    const int kst = cc >> 2, lgv = cc & 3;
    const size_t idx = ((((size_t)b*8 + cg)*4 + kst)*64 + (lgv*16 + (c & 15)))*8;
    short8 hh, ll;
#pragma unroll
    for (int i=0;i<8;i++){
        float val = gm*a[i] + ((c0 + i) == c ? 1.f : 0.f);   // M' = gm*M + I
        short hb, lb; cv2(val, hb, lb);
        hh[i]=hb; ll[i]=lb;
    }
    *(short8*)(Mh_ + idx) = hh;
    *(short8*)(Ml_ + idx) = ll;
    if (cc == 0) cvg[b*NC + c] = gm*(cv + bo[c]);
}

// ---- K4: out = M' x + cvg  (A = x from swizzled Xt; B = M' hi/lo) ----
// (round-9 verbatim, PASSING)
__global__ __launch_bounds__(256, 4) void k_final(const float* __restrict__ x,
        const short* __restrict__ Mh_, const short* __restrict__ Ml_,
        const float* __restrict__ cvg, float* __restrict__ out){
    __shared__ short Xt[NC*128];   // 32 KB: row n (local), 16 slots of 8 shorts
    const int b   = blockIdx.y;
    const int n0  = blockIdx.x * 128;
    const int tid = threadIdx.x;
    const int wid = tid >> 6, lane = tid & 63;
    const int l16 = lane & 15, lgi = lane >> 4;

    // ---- stage: thread (nr = tid&31, mb8 = tid>>5), 2 reps
    const int nr = tid & 31, mb8 = tid >> 5;
    const float* xs = x + (size_t)b*NC*NHW + n0 + nr*4;
#pragma unroll
    for (int rep=0; rep<2; rep++){
        const int m0 = rep*64 + mb8*8;
        const float* xm = xs + (size_t)m0*NHW;
        f32x4 v0 = *(const f32x4*)(xm);
        f32x4 v1 = *(const f32x4*)(xm + (size_t)1*NHW);
        f32x4 v2 = *(const f32x4*)(xm + (size_t)2*NHW);
        f32x4 v3 = *(const f32x4*)(xm + (size_t)3*NHW);
        f32x4 v4 = *(const f32x4*)(xm + (size_t)4*NHW);
        f32x4 v5 = *(const f32x4*)(xm + (size_t)5*NHW);
        f32x4 v6 = *(const f32x4*)(xm + (size_t)6*NHW);
        f32x4 v7 = *(const f32x4*)(xm + (size_t)7*NHW);
#pragma unroll
        for (int r=0;r<4;r++){
            short8 w;
            w[0]=bfbits(v0[r]); w[1]=bfbits(v1[r]); w[2]=bfbits(v2[r]); w[3]=bfbits(v3[r]);
            w[4]=bfbits(v4[r]); w[5]=bfbits(v5[r]); w[6]=bfbits(v6[r]); w[7]=bfbits(v7[r]);
            const int n = nr*4 + r;
            const int slot = (rep*8 + mb8) ^ ((n>>2)&15) ^ ((n&3)<<2);
            *(short8*)(&Xt[n*128 + slot*8]) = w;
        }
    }
    __syncthreads();

    f32x4 acc[2][8];   // [n 16-block t][cg]
#pragma unroll
    for (int t=0;t<2;t++)
#pragma unroll
      for (int g=0;g<8;g++) acc[t][g]=zero4();

    const short* Mh = Mh_ + (size_t)b*16384;
    const short* Ml = Ml_ + (size_t)b*16384;

#pragma unroll
    for (int ks=0; ks<4; ks++){
        const int nA0 = wid*32 + l16;
        const int nA1 = nA0 + 16;
        const int sl  = ks*4 + lgi;
        const int s0  = sl ^ ((nA0>>2)&15) ^ ((nA0&3)<<2);
        const int s1  = sl ^ ((nA1>>2)&15) ^ ((nA1&3)<<2);
        short8 a0 = *(const short8*)(&Xt[nA0*128 + s0*8]);
        short8 a1 = *(const short8*)(&Xt[nA1*128 + s1*8]);
#pragma unroll
        for (int cg=0; cg<8; cg++){
            const size_t bi = (((size_t)cg*4 + ks)*64 + lane)*8;
            short8 bh = *(const short8*)(Mh + bi);
            short8 bl = *(const short8*)(Ml + bi);
            acc[0][cg] = __builtin_amdgcn_mfma_f32_16x16x32_bf16(a0, bh, acc[0][cg], 0,0,0);
            acc[0][cg] = __builtin_amdgcn_mfma_f32_16x16x32_bf16(a0, bl, acc[0][cg], 0,0,0);
            acc[1][cg] = __builtin_amdgcn_mfma_f32_16x16x32_bf16(a1, bh, acc[1][cg], 0,0,0);
            acc[1][cg] = __builtin_amdgcn_mfma_f32_16x16x32_bf16(a1, bl, acc[1][cg], 0,0,0);
        }
    }

    // C/D: row(i)=n-offset=(lane>>4)*4+r, col(j)=c=cg*16+(lane&15)
    const float* cb = cvg + b*NC;
#pragma unroll
    for (int cg=0;cg<8;cg++){
        const int c = cg*16 + l16;
        const float ccv = cb[c];
        float* orow = &out[((size_t)b*NC + c)*NHW + n0 + wid*32 + lgi*4];
#pragma unroll
        for (int t=0;t<2;t++){
            f32x4 o = acc[t][cg];
            o[0]+=ccv; o[1]+=ccv; o[2]+=ccv; o[3]+=ccv;
            *(f32x4*)(orow + t*16) = o;
        }
    }
}

extern "C" void kernel_launch(void* const* d_in, const int* in_sizes, int n_in,
                              void* d_out, int out_size, void* d_ws, size_t ws_size,
                              hipStream_t stream){
    const float* x     = (const float*)d_in[0];
    const float* Wq    = (const float*)d_in[1];
    const float* bq    = (const float*)d_in[2];
    const float* Wk    = (const float*)d_in[3];
    const float* bk    = (const float*)d_in[4];
    const float* Wv    = (const float*)d_in[5];
    const float* bv    = (const float*)d_in[6];
    const float* Wo    = (const float*)d_in[7];
    const float* bo    = (const float*)d_in[8];
    const float* gamma = (const float*)d_in[9];
    float* out = (float*)d_out;

    float* w  = (float*)d_ws;
    float* G  = w + GOFF;
    float* S  = w + SOFF;
    float* T  = w + TOFF;
    float* R  = w + ROFF;
    float* CV = w + CVOFF;
    short* Mh = (short*)(w + MHOFF);
    short* Ml = (short*)(w + MLOFF);

    // zero atomic-accumulation targets (G: 131072 + svec: 1024 floats)
    k_zero    <<<dim3(129),     256, 0, stream>>>(G);

    k_gram    <<<dim3(128, NB), 256, 0, stream>>>(x, G, S);
    k_energyav<<<dim3(8,   NB), 256, 0, stream>>>(G, S, Wq, bq, Wk, bk, bv, Wv, R, T);
    k_om      <<<dim3(8,   NB), 256, 0, stream>>>(R, Wo, bo, T, gamma, Mh, Ml, CV);
    k_final   <<<dim3(288, NB), 256, 0, stream>>>(x, Mh, Ml, CV, out);
}

// Round 12
// 211.562 us; speedup vs baseline: 1.0944x; 1.0725x over previous
//
#include <hip/hip_runtime.h>
#include <cstdint>
#include <cstddef>

#define NB  8
#define NC  128
#define NHW 36864

// workspace layout (float offsets)
#define GOFF  0         // 131072
#define SOFF  131072    // 1024
#define TOFF  132096    // 1024
#define ROFF  133120    // 131072
#define CVOFF 264192    // 1024
#define MHOFF 265216    // 65536 floats = 131072 shorts (bf16 M' hi fragments)
#define MLOFF 330752    // 65536 floats = 131072 shorts (bf16 M' lo fragments)

typedef __attribute__((ext_vector_type(8))) short short8;
typedef __attribute__((ext_vector_type(4))) float f32x4;

static __device__ __forceinline__ f32x4 zero4(){ f32x4 v = {0.f,0.f,0.f,0.f}; return v; }

// float -> bf16 bits via native __bf16 (compiler emits v_cvt_pk_bf16_f32 pairs)
static __device__ __forceinline__ short bfbits(float f){
    union { __bf16 b; short s; } u; u.b = (__bf16)f; return u.s;
}
// hi/lo split: h = bf16(f), l = bf16(f - float(h))
static __device__ __forceinline__ void cv2(float f, short& hb, short& lb){
    union { __bf16 b; short s; } u;
    u.b = (__bf16)f; hb = u.s;
    float hf = (float)u.b;
    u.b = (__bf16)(f - hf); lb = u.s;
}
// two f32x4 (8 consecutive cols) -> hi/lo short8 fragments; returns sum
static __device__ __forceinline__ float cv8(f32x4 v0, f32x4 v1, short8& h, short8& l){
    float ss = 0.f;
#pragma unroll
    for (int j=0;j<4;j++){
        short hb, lb;
        cv2(v0[j], hb, lb); h[j]   = hb; l[j]   = lb;
        cv2(v1[j], hb, lb); h[4+j] = hb; l[4+j] = lb;
        ss += v0[j] + v1[j];
    }
    return ss;
}

// ---- K0: zero G and svec (atomic accumulation targets) ----
__global__ __launch_bounds__(256) void k_zero(float* __restrict__ p){
    const int i = (blockIdx.x*256 + threadIdx.x)*4;
    *(f32x4*)(p + i) = zero4();
}

// ======================= K1: Gram G = sum_n x x^T ==========================
// Convert-ONCE bf16 staging (round-11 structure, PASSING). SINGLE CHANGE:
// chunks 128 -> 32 (256 blocks = 1/CU, 36 tiles each) to cut the contended
// atomic epilogue 4x (16.8M -> 4.2M fp32 atomics; WRITE 66 -> 16.5 MB) —
// the measured invariant limiting this kernel. Also gives 4.6 KB contiguous
// reads per row (DRAM page locality).
#define GNT 36          // 36 tiles * 32 n = 1152 n per chunk
#define GLDH 5120       // shorts per (buf,half): 128*40

__global__ __launch_bounds__(256) void k_gram(const float* __restrict__ x,
                                              float* __restrict__ G,
                                              float* __restrict__ svec){
    __shared__ short Ls[2][2][GLDH];   // [buf][hi/lo][row*40+col] : 40 KB
    const int b     = blockIdx.y;
    const int chunk = blockIdx.x;      // 32 chunks * 1152 n
    const int tid   = threadIdx.x;
    const int wid   = tid >> 6, lane = tid & 63;
    const int l16   = lane & 15, lgi = lane >> 4;
    const int sr    = tid >> 1;          // staging row (0..127)
    const int sh    = (tid & 1) * 16;    // staging col-half (0|16)

    const float* xs = x + (size_t)b*NC*NHW + (size_t)sr*NHW + chunk*1152 + sh;

    float srow = 0.f;
    f32x4 acc[2][8];
#pragma unroll
    for (int p=0;p<2;p++)
#pragma unroll
      for (int g=0;g<8;g++) acc[p][g] = zero4();

    // prologue: stage tile 0 into buf 0
    {
        f32x4 v0 = *(const f32x4*)(xs);
        f32x4 v1 = *(const f32x4*)(xs+4);
        f32x4 v2 = *(const f32x4*)(xs+8);
        f32x4 v3 = *(const f32x4*)(xs+12);
        short8 h0,l0,h1,l1;
        srow += cv8(v0,v1,h0,l0) + cv8(v2,v3,h1,l1);
        short* dh = &Ls[0][0][sr*40 + sh];
        short* dl = &Ls[0][1][sr*40 + sh];
        *(short8*)dh = h0; *(short8*)(dh+8) = h1;
        *(short8*)dl = l0; *(short8*)(dl+8) = l1;
    }
    __syncthreads();

    for (int t=0; t<GNT; ++t){
        f32x4 v0,v1,v2,v3;
        const bool pf = (t+1 < GNT);
        if (pf){                            // issue next-tile loads EARLY (T14)
            const float* p = xs + (t+1)*32;
            v0 = *(const f32x4*)(p);   v1 = *(const f32x4*)(p+4);
            v2 = *(const f32x4*)(p+8); v3 = *(const f32x4*)(p+12);
        }
        {   // compute on buf t&1
            const short* Lh = Ls[t&1][0];
            const short* Ll = Ls[t&1][1];
            const int ra0 = (wid*32      + l16)*40 + lgi*8;
            const int ra1 = (wid*32 + 16 + l16)*40 + lgi*8;
            short8 hA0 = *(const short8*)(Lh + ra0);
            short8 lA0 = *(const short8*)(Ll + ra0);
            short8 hA1 = *(const short8*)(Lh + ra1);
            short8 lA1 = *(const short8*)(Ll + ra1);
#pragma unroll
            for (int g=0; g<8; g++){
                const int rb = (g*16 + l16)*40 + lgi*8;
                short8 hg  = *(const short8*)(Lh + rb);
                short8 lg2 = *(const short8*)(Ll + rb);
                acc[0][g] = __builtin_amdgcn_mfma_f32_16x16x32_bf16(hA0, hg,  acc[0][g], 0,0,0);
                acc[0][g] = __builtin_amdgcn_mfma_f32_16x16x32_bf16(hA0, lg2, acc[0][g], 0,0,0);
                acc[0][g] = __builtin_amdgcn_mfma_f32_16x16x32_bf16(lA0, hg,  acc[0][g], 0,0,0);
                acc[1][g] = __builtin_amdgcn_mfma_f32_16x16x32_bf16(hA1, hg,  acc[1][g], 0,0,0);
                acc[1][g] = __builtin_amdgcn_mfma_f32_16x16x32_bf16(hA1, lg2, acc[1][g], 0,0,0);
                acc[1][g] = __builtin_amdgcn_mfma_f32_16x16x32_bf16(lA1, hg,  acc[1][g], 0,0,0);
            }
        }
        if (pf){                            // convert + write LATE (other buf)
            short8 h0,l0,h1,l1;
            srow += cv8(v0,v1,h0,l0) + cv8(v2,v3,h1,l1);
            short* dh = &Ls[(t+1)&1][0][sr*40 + sh];
            short* dl = &Ls[(t+1)&1][1][sr*40 + sh];
            *(short8*)dh = h0; *(short8*)(dh+8) = h1;
            *(short8*)dl = l0; *(short8*)(dl+8) = l1;
        }
        __syncthreads();
    }

    // C/D layout (pass-verified): col = lane&15, row = (lane>>4)*4 + reg
    float* Gb = G + (size_t)b*NC*NC;
#pragma unroll
    for (int p=0;p<2;p++){
        const int rg = wid*2 + p;
#pragma unroll
        for (int g=0;g<8;g++){
#pragma unroll
            for (int r=0;r<4;r++){
                atomicAdd(&Gb[(size_t)(rg*16 + lgi*4 + r)*NC + g*16 + l16], acc[p][g][r]);
            }
        }
    }
    srow += __shfl_xor(srow, 1);
    if ((tid & 1) == 0) atomicAdd(&svec[b*NC + sr], srow);
}

// ---- K2: energy = Wq G Wk^T + rank-1 terms; softmax -> A (LDS); t = A bv; R = A Wv ----
// (round-11 verbatim, PASSING)
__global__ __launch_bounds__(256) void k_energyav(const float* __restrict__ G,
        const float* __restrict__ svec,
        const float* __restrict__ Wq, const float* __restrict__ bq,
        const float* __restrict__ Wk, const float* __restrict__ bk,
        const float* __restrict__ bv, const float* __restrict__ Wv,
        float* __restrict__ R, float* __restrict__ tvec){
    const int b  = blockIdx.y;
    const int d0 = blockIdx.x * 16;
    const int tid = threadIdx.x;
    const int d  = tid & 15;
    const int ec = tid >> 4;

    __shared__ float Ps[16][128];
    __shared__ float Es[16][128];
    __shared__ float red[16][16];
    __shared__ float rowmax[16];
    __shared__ float rowsum[16];
    __shared__ float qs[16];

    const float* Wqrow = Wq + (size_t)(d0 + d)*NC;
    const float* sb = svec + b*NC;
#pragma unroll
    for (int i=0;i<8;i++){
        const int c = ec*8 + i;
        const float* Grow = G + ((size_t)b*NC + c)*NC;
        float a = 0.f;
        for (int c4=0;c4<32;c4++){
            f32x4 g4 = *(const f32x4*)(Grow + c4*4);
            f32x4 w4 = *(const f32x4*)(Wqrow + c4*4);
            a += g4[0]*w4[0] + g4[1]*w4[1] + g4[2]*w4[2] + g4[3]*w4[3];
        }
        Ps[d][c] = a;
    }
    if (ec == 0){
        float a = 0.f;
        for (int c4=0;c4<32;c4++){
            f32x4 w4 = *(const f32x4*)(Wqrow + c4*4);
            f32x4 s4 = *(const f32x4*)(sb + c4*4);
            a += w4[0]*s4[0] + w4[1]*s4[1] + w4[2]*s4[2] + w4[3]*s4[3];
        }
        qs[d] = a;
    }
    __syncthreads();
    const float bqd = bq[d0+d];
#pragma unroll
    for (int i=0;i<8;i++){
        const int e = ec*8 + i;
        const float* Wkrow = Wk + (size_t)e*NC;
        float ea = 0.f, ks = 0.f;
        for (int c4=0;c4<32;c4++){
            f32x4 w4 = *(const f32x4*)(Wkrow + c4*4);
            f32x4 p4 = *(const f32x4*)(&Ps[d][c4*4]);
            f32x4 s4 = *(const f32x4*)(sb + c4*4);
            ea += w4[0]*p4[0]+w4[1]*p4[1]+w4[2]*p4[2]+w4[3]*p4[3];
            ks += w4[0]*s4[0]+w4[1]*s4[1]+w4[2]*s4[2]+w4[3]*s4[3];
        }
        const float bke = bk[e];
        Es[d][e] = ea + bke*qs[d] + bqd*ks + (float)NHW*bqd*bke;
    }
    float m8 = -3.4e38f;
#pragma unroll
    for (int i=0;i<8;i++) m8 = fmaxf(m8, Es[d][ec*8+i]);
    red[d][ec] = m8;
    __syncthreads();
    if (tid < 16){
        float m = red[tid][0];
        for (int j=1;j<16;j++) m = fmaxf(m, red[tid][j]);
        rowmax[tid] = m;
    }
    __syncthreads();
    const float rm = rowmax[d];
    float s8 = 0.f;
#pragma unroll
    for (int i=0;i<8;i++){
        float ex = expf(Es[d][ec*8+i] - rm);
        Es[d][ec*8+i] = ex;
        s8 += ex;
    }
    red[d][ec] = s8;
    __syncthreads();
    if (tid < 16){
        float sm = 0.f;
        for (int j=0;j<16;j++) sm += red[tid][j];
        rowsum[tid] = sm;
    }
    __syncthreads();
    const float inv = 1.f / rowsum[d];
    float ta = 0.f;
#pragma unroll
    for (int i=0;i<8;i++){
        const int e = ec*8 + i;
        float av = Es[d][e] * inv;
        Es[d][e] = av;
        ta += av * bv[e];
    }
    red[d][ec] = ta;
    __syncthreads();
    if (tid < 16){
        float sm = 0.f;
        for (int j=0;j<16;j++) sm += red[tid][j];
        tvec[b*NC + d0 + tid] = sm;
    }
    const int c0 = ec*8;
    float racc[8];
#pragma unroll
    for (int i=0;i<8;i++) racc[i]=0.f;
    for (int e=0;e<NC;e++){
        const float av = Es[d][e];
        const float* wv = Wv + (size_t)e*NC + c0;
        f32x4 w0 = *(const f32x4*)wv;
        f32x4 w1 = *(const f32x4*)(wv+4);
        racc[0]+=av*w0[0]; racc[1]+=av*w0[1]; racc[2]+=av*w0[2]; racc[3]+=av*w0[3];
        racc[4]+=av*w1[0]; racc[5]+=av*w1[1]; racc[6]+=av*w1[2]; racc[7]+=av*w1[3];
    }
    float* Rrow = R + ((size_t)b*NC + d0 + d)*NC + c0;
#pragma unroll
    for (int i=0;i<8;i++) Rrow[i] = racc[i];
}

// ---- K3: M' = gamma*Wo*R + I -> hi/lo bf16 B-fragments; cvg = gamma*(Wo t + bo) ----
// (round-11 verbatim, PASSING)
__global__ __launch_bounds__(256) void k_om(const float* __restrict__ R,
        const float* __restrict__ Wo, const float* __restrict__ bo,
        const float* __restrict__ tvec, const float* __restrict__ gamma,
        short* __restrict__ Mh_, short* __restrict__ Ml_, float* __restrict__ cvg){
    const int b = blockIdx.y, o0 = blockIdx.x*16;
    const int tid = threadIdx.x, o = tid&15, cc = tid>>4;
    const int c0 = cc*8;                      // cin octet base
    const float* Worow = Wo + (size_t)(o0+o)*NC;
    const float* tb = tvec + b*NC;
    float a[8];
#pragma unroll
    for (int i=0;i<8;i++) a[i]=0.f;
    float cv = 0.f;
    for (int dd=0; dd<NC; dd++){
        const float wv = Worow[dd];
        const float* r = R + ((size_t)b*NC + dd)*NC + c0;
        f32x4 r0 = *(const f32x4*)r;
        f32x4 r1 = *(const f32x4*)(r+4);
        a[0]+=wv*r0[0]; a[1]+=wv*r0[1]; a[2]+=wv*r0[2]; a[3]+=wv*r0[3];
        a[4]+=wv*r1[0]; a[5]+=wv*r1[1]; a[6]+=wv*r1[2]; a[7]+=wv*r1[3];
        cv += wv*tb[dd];
    }
    const float gm = gamma[0];
    const int c   = o0 + o;
    const int cg  = c >> 4;
    const int kst = cc >> 2, lgv = cc & 3;
    const size_t idx = ((((size_t)b*8 + cg)*4 + kst)*64 + (lgv*16 + (c & 15)))*8;
    short8 hh, ll;
#pragma unroll
    for (int i=0;i<8;i++){
        float val = gm*a[i] + ((c0 + i) == c ? 1.f : 0.f);   // M' = gm*M + I
        short hb, lb; cv2(val, hb, lb);
        hh[i]=hb; ll[i]=lb;
    }
    *(short8*)(Mh_ + idx) = hh;
    *(short8*)(Ml_ + idx) = ll;
    if (cc == 0) cvg[b*NC + c] = gm*(cv + bo[c]);
}

// ---- K4: out = M' x + cvg  (A = x from swizzled Xt; B = M' hi/lo) ----
// (round-11 verbatim, PASSING)
__global__ __launch_bounds__(256, 4) void k_final(const float* __restrict__ x,
        const short* __restrict__ Mh_, const short* __restrict__ Ml_,
        const float* __restrict__ cvg, float* __restrict__ out){
    __shared__ short Xt[NC*128];   // 32 KB: row n (local), 16 slots of 8 shorts
    const int b   = blockIdx.y;
    const int n0  = blockIdx.x * 128;
    const int tid = threadIdx.x;
    const int wid = tid >> 6, lane = tid & 63;
    const int l16 = lane & 15, lgi = lane >> 4;

    // ---- stage: thread (nr = tid&31, mb8 = tid>>5), 2 reps
    const int nr = tid & 31, mb8 = tid >> 5;
    const float* xs = x + (size_t)b*NC*NHW + n0 + nr*4;
#pragma unroll
    for (int rep=0; rep<2; rep++){
        const int m0 = rep*64 + mb8*8;
        const float* xm = xs + (size_t)m0*NHW;
        f32x4 v0 = *(const f32x4*)(xm);
        f32x4 v1 = *(const f32x4*)(xm + (size_t)1*NHW);
        f32x4 v2 = *(const f32x4*)(xm + (size_t)2*NHW);
        f32x4 v3 = *(const f32x4*)(xm + (size_t)3*NHW);
        f32x4 v4 = *(const f32x4*)(xm + (size_t)4*NHW);
        f32x4 v5 = *(const f32x4*)(xm + (size_t)5*NHW);
        f32x4 v6 = *(const f32x4*)(xm + (size_t)6*NHW);
        f32x4 v7 = *(const f32x4*)(xm + (size_t)7*NHW);
#pragma unroll
        for (int r=0;r<4;r++){
            short8 w;
            w[0]=bfbits(v0[r]); w[1]=bfbits(v1[r]); w[2]=bfbits(v2[r]); w[3]=bfbits(v3[r]);
            w[4]=bfbits(v4[r]); w[5]=bfbits(v5[r]); w[6]=bfbits(v6[r]); w[7]=bfbits(v7[r]);
            const int n = nr*4 + r;
            const int slot = (rep*8 + mb8) ^ ((n>>2)&15) ^ ((n&3)<<2);
            *(short8*)(&Xt[n*128 + slot*8]) = w;
        }
    }
    __syncthreads();

    f32x4 acc[2][8];   // [n 16-block t][cg]
#pragma unroll
    for (int t=0;t<2;t++)
#pragma unroll
      for (int g=0;g<8;g++) acc[t][g]=zero4();

    const short* Mh = Mh_ + (size_t)b*16384;
    const short* Ml = Ml_ + (size_t)b*16384;

#pragma unroll
    for (int ks=0; ks<4; ks++){
        const int nA0 = wid*32 + l16;
        const int nA1 = nA0 + 16;
        const int sl  = ks*4 + lgi;
        const int s0  = sl ^ ((nA0>>2)&15) ^ ((nA0&3)<<2);
        const int s1  = sl ^ ((nA1>>2)&15) ^ ((nA1&3)<<2);
        short8 a0 = *(const short8*)(&Xt[nA0*128 + s0*8]);
        short8 a1 = *(const short8*)(&Xt[nA1*128 + s1*8]);
#pragma unroll
        for (int cg=0; cg<8; cg++){
            const size_t bi = (((size_t)cg*4 + ks)*64 + lane)*8;
            short8 bh = *(const short8*)(Mh + bi);
            short8 bl = *(const short8*)(Ml + bi);
            acc[0][cg] = __builtin_amdgcn_mfma_f32_16x16x32_bf16(a0, bh, acc[0][cg], 0,0,0);
            acc[0][cg] = __builtin_amdgcn_mfma_f32_16x16x32_bf16(a0, bl, acc[0][cg], 0,0,0);
            acc[1][cg] = __builtin_amdgcn_mfma_f32_16x16x32_bf16(a1, bh, acc[1][cg], 0,0,0);
            acc[1][cg] = __builtin_amdgcn_mfma_f32_16x16x32_bf16(a1, bl, acc[1][cg], 0,0,0);
        }
    }

    // C/D: row(i)=n-offset=(lane>>4)*4+r, col(j)=c=cg*16+(lane&15)
    const float* cb = cvg + b*NC;
#pragma unroll
    for (int cg=0;cg<8;cg++){
        const int c = cg*16 + l16;
        const float ccv = cb[c];
        float* orow = &out[((size_t)b*NC + c)*NHW + n0 + wid*32 + lgi*4];
#pragma unroll
        for (int t=0;t<2;t++){
            f32x4 o = acc[t][cg];
            o[0]+=ccv; o[1]+=ccv; o[2]+=ccv; o[3]+=ccv;
            *(f32x4*)(orow + t*16) = o;
        }
    }
}

extern "C" void kernel_launch(void* const* d_in, const int* in_sizes, int n_in,
                              void* d_out, int out_size, void* d_ws, size_t ws_size,
                              hipStream_t stream){
    const float* x     = (const float*)d_in[0];
    const float* Wq    = (const float*)d_in[1];
    const float* bq    = (const float*)d_in[2];
    const float* Wk    = (const float*)d_in[3];
    const float* bk    = (const float*)d_in[4];
    const float* Wv    = (const float*)d_in[5];
    const float* bv    = (const float*)d_in[6];
    const float* Wo    = (const float*)d_in[7];
    const float* bo    = (const float*)d_in[8];
    const float* gamma = (const float*)d_in[9];
    float* out = (float*)d_out;

    float* w  = (float*)d_ws;
    float* G  = w + GOFF;
    float* S  = w + SOFF;
    float* T  = w + TOFF;
    float* R  = w + ROFF;
    float* CV = w + CVOFF;
    short* Mh = (short*)(w + MHOFF);
    short* Ml = (short*)(w + MLOFF);

    // zero atomic-accumulation targets (G: 131072 + svec: 1024 floats)
    k_zero    <<<dim3(129),     256, 0, stream>>>(G);

    k_gram    <<<dim3(32,  NB), 256, 0, stream>>>(x, G, S);
    k_energyav<<<dim3(8,   NB), 256, 0, stream>>>(G, S, Wq, bq, Wk, bk, bv, Wv, R, T);
    k_om      <<<dim3(8,   NB), 256, 0, stream>>>(R, Wo, bo, T, gamma, Mh, Ml, CV);
    k_final   <<<dim3(288, NB), 256, 0, stream>>>(x, Mh, Ml, CV, out);
}

// Round 13
// 195.652 us; speedup vs baseline: 1.1834x; 1.0813x over previous
//
#include <hip/hip_runtime.h>
#include <cstdint>
#include <cstddef>

#define NB  8
#define NC  128
#define NHW 36864

// workspace layout (float offsets)
#define GOFF  0         // 131072
#define SOFF  131072    // 1024
#define TOFF  132096    // 1024
#define ROFF  133120    // 131072
#define CVOFF 264192    // 1024
#define MHOFF 265216    // 65536 floats = 131072 shorts (bf16 M' hi fragments)
#define MLOFF 330752    // 65536 floats = 131072 shorts (bf16 M' lo fragments)

typedef __attribute__((ext_vector_type(8))) short short8;
typedef __attribute__((ext_vector_type(4))) float f32x4;

static __device__ __forceinline__ f32x4 zero4(){ f32x4 v = {0.f,0.f,0.f,0.f}; return v; }

// float -> bf16 bits via native __bf16 (compiler emits v_cvt_pk_bf16_f32 pairs)
static __device__ __forceinline__ short bfbits(float f){
    union { __bf16 b; short s; } u; u.b = (__bf16)f; return u.s;
}
// hi/lo split: h = bf16(f), l = bf16(f - float(h))
static __device__ __forceinline__ void cv2(float f, short& hb, short& lb){
    union { __bf16 b; short s; } u;
    u.b = (__bf16)f; hb = u.s;
    float hf = (float)u.b;
    u.b = (__bf16)(f - hf); lb = u.s;
}
// two f32x4 (8 consecutive cols) -> hi/lo short8 fragments; returns sum
static __device__ __forceinline__ float cv8(f32x4 v0, f32x4 v1, short8& h, short8& l){
    float ss = 0.f;
#pragma unroll
    for (int j=0;j<4;j++){
        short hb, lb;
        cv2(v0[j], hb, lb); h[j]   = hb; l[j]   = lb;
        cv2(v1[j], hb, lb); h[4+j] = hb; l[4+j] = lb;
        ss += v0[j] + v1[j];
    }
    return ss;
}

// ---- K0: zero G and svec (atomic accumulation targets) ----
__global__ __launch_bounds__(256) void k_zero(float* __restrict__ p){
    const int i = (blockIdx.x*256 + threadIdx.x)*4;
    *(f32x4*)(p + i) = zero4();
}

// ======================= K1: Gram G = sum_n x x^T ==========================
// 512-thread / 8-wave version: each wave owns ONE 16-row A-rowgroup (wid),
// computing acc[8] vs all 8 col-groups (24 MFMA/tile/wave, 18 ds_read_b128).
// 2 waves/SIMD for TLP. Staging: thread=(row=tid>>2, coloct=(tid&3)*8),
// convert-once hi/lo bf16, ds_write_b128 (stride 40 shorts: 2-way banks).
// Prefetch loads are UNCONDITIONAL at top of the peeled loop body +
// sched_barrier(0) so they cannot sink to their use point.
#define GNT 36          // 36 tiles * 32 n = 1152 n per chunk
#define GLDH 5120       // shorts per (buf,half): 128*40

__global__ __launch_bounds__(512) void k_gram(const float* __restrict__ x,
                                              float* __restrict__ G,
                                              float* __restrict__ svec){
    __shared__ short Ls[2][2][GLDH];   // [buf][hi/lo][row*40+col] : 40 KB
    const int b     = blockIdx.y;
    const int chunk = blockIdx.x;      // 32 chunks * 1152 n
    const int tid   = threadIdx.x;
    const int wid   = tid >> 6, lane = tid & 63;
    const int l16   = lane & 15, lgi = lane >> 4;
    const int sr    = tid >> 2;          // staging row (0..127)
    const int sc    = (tid & 3) * 8;     // staging col-octet (0,8,16,24)

    const float* xs = x + (size_t)b*NC*NHW + (size_t)sr*NHW + chunk*1152 + sc;

    float srow = 0.f;
    f32x4 acc[8];
#pragma unroll
    for (int g=0;g<8;g++) acc[g] = zero4();

    const int ra = (wid*16 + l16)*40 + lgi*8;   // this wave's A-fragment addr

    // prologue: stage tile 0 into buf 0
    {
        f32x4 v0 = *(const f32x4*)(xs);
        f32x4 v1 = *(const f32x4*)(xs+4);
        short8 h0,l0;
        srow += cv8(v0,v1,h0,l0);
        *(short8*)&Ls[0][0][sr*40 + sc] = h0;
        *(short8*)&Ls[0][1][sr*40 + sc] = l0;
    }
    __syncthreads();

    for (int t=0; t<GNT-1; ++t){
        // 1. issue next-tile loads (unconditional; pinned by sched_barrier)
        const float* p = xs + (t+1)*32;
        f32x4 v0 = *(const f32x4*)(p);
        f32x4 v1 = *(const f32x4*)(p+4);
        __builtin_amdgcn_sched_barrier(0);

        // 2. compute on buf t&1
        {
            const short* Lh = Ls[t&1][0];
            const short* Ll = Ls[t&1][1];
            short8 hA = *(const short8*)(Lh + ra);
            short8 lA = *(const short8*)(Ll + ra);
#pragma unroll
            for (int g=0; g<8; g++){
                const int rb = (g*16 + l16)*40 + lgi*8;
                short8 hg  = *(const short8*)(Lh + rb);
                short8 lg2 = *(const short8*)(Ll + rb);
                acc[g] = __builtin_amdgcn_mfma_f32_16x16x32_bf16(hA, hg,  acc[g], 0,0,0);
                acc[g] = __builtin_amdgcn_mfma_f32_16x16x32_bf16(hA, lg2, acc[g], 0,0,0);
                acc[g] = __builtin_amdgcn_mfma_f32_16x16x32_bf16(lA, hg,  acc[g], 0,0,0);
            }
        }

        // 3. convert + write into the other buffer
        {
            short8 h0,l0;
            srow += cv8(v0,v1,h0,l0);
            *(short8*)&Ls[(t+1)&1][0][sr*40 + sc] = h0;
            *(short8*)&Ls[(t+1)&1][1][sr*40 + sc] = l0;
        }
        __syncthreads();
    }

    // epilogue: compute last tile (buf (GNT-1)&1)
    {
        const short* Lh = Ls[(GNT-1)&1][0];
        const short* Ll = Ls[(GNT-1)&1][1];
        short8 hA = *(const short8*)(Lh + ra);
        short8 lA = *(const short8*)(Ll + ra);
#pragma unroll
        for (int g=0; g<8; g++){
            const int rb = (g*16 + l16)*40 + lgi*8;
            short8 hg  = *(const short8*)(Lh + rb);
            short8 lg2 = *(const short8*)(Ll + rb);
            acc[g] = __builtin_amdgcn_mfma_f32_16x16x32_bf16(hA, hg,  acc[g], 0,0,0);
            acc[g] = __builtin_amdgcn_mfma_f32_16x16x32_bf16(hA, lg2, acc[g], 0,0,0);
            acc[g] = __builtin_amdgcn_mfma_f32_16x16x32_bf16(lA, hg,  acc[g], 0,0,0);
        }
    }

    // C/D layout (pass-verified): col = lane&15, row = (lane>>4)*4 + reg
    float* Gb = G + (size_t)b*NC*NC;
#pragma unroll
    for (int g=0;g<8;g++){
#pragma unroll
        for (int r=0;r<4;r++){
            atomicAdd(&Gb[(size_t)(wid*16 + lgi*4 + r)*NC + g*16 + l16], acc[g][r]);
        }
    }
    srow += __shfl_xor(srow, 1);
    srow += __shfl_xor(srow, 2);
    if ((tid & 3) == 0) atomicAdd(&svec[b*NC + sr], srow);
}

// ---- K2: energy = Wq G Wk^T + rank-1 terms; softmax -> A (LDS); t = A bv; R = A Wv ----
// (round-12 verbatim, PASSING)
__global__ __launch_bounds__(256) void k_energyav(const float* __restrict__ G,
        const float* __restrict__ svec,
        const float* __restrict__ Wq, const float* __restrict__ bq,
        const float* __restrict__ Wk, const float* __restrict__ bk,
        const float* __restrict__ bv, const float* __restrict__ Wv,
        float* __restrict__ R, float* __restrict__ tvec){
    const int b  = blockIdx.y;
    const int d0 = blockIdx.x * 16;
    const int tid = threadIdx.x;
    const int d  = tid & 15;
    const int ec = tid >> 4;

    __shared__ float Ps[16][128];
    __shared__ float Es[16][128];
    __shared__ float red[16][16];
    __shared__ float rowmax[16];
    __shared__ float rowsum[16];
    __shared__ float qs[16];

    const float* Wqrow = Wq + (size_t)(d0 + d)*NC;
    const float* sb = svec + b*NC;
#pragma unroll
    for (int i=0;i<8;i++){
        const int c = ec*8 + i;
        const float* Grow = G + ((size_t)b*NC + c)*NC;
        float a = 0.f;
        for (int c4=0;c4<32;c4++){
            f32x4 g4 = *(const f32x4*)(Grow + c4*4);
            f32x4 w4 = *(const f32x4*)(Wqrow + c4*4);
            a += g4[0]*w4[0] + g4[1]*w4[1] + g4[2]*w4[2] + g4[3]*w4[3];
        }
        Ps[d][c] = a;
    }
    if (ec == 0){
        float a = 0.f;
        for (int c4=0;c4<32;c4++){
            f32x4 w4 = *(const f32x4*)(Wqrow + c4*4);
            f32x4 s4 = *(const f32x4*)(sb + c4*4);
            a += w4[0]*s4[0] + w4[1]*s4[1] + w4[2]*s4[2] + w4[3]*s4[3];
        }
        qs[d] = a;
    }
    __syncthreads();
    const float bqd = bq[d0+d];
#pragma unroll
    for (int i=0;i<8;i++){
        const int e = ec*8 + i;
        const float* Wkrow = Wk + (size_t)e*NC;
        float ea = 0.f, ks = 0.f;
        for (int c4=0;c4<32;c4++){
            f32x4 w4 = *(const f32x4*)(Wkrow + c4*4);
            f32x4 p4 = *(const f32x4*)(&Ps[d][c4*4]);
            f32x4 s4 = *(const f32x4*)(sb + c4*4);
            ea += w4[0]*p4[0]+w4[1]*p4[1]+w4[2]*p4[2]+w4[3]*p4[3];
            ks += w4[0]*s4[0]+w4[1]*s4[1]+w4[2]*s4[2]+w4[3]*s4[3];
        }
        const float bke = bk[e];
        Es[d][e] = ea + bke*qs[d] + bqd*ks + (float)NHW*bqd*bke;
    }
    float m8 = -3.4e38f;
#pragma unroll
    for (int i=0;i<8;i++) m8 = fmaxf(m8, Es[d][ec*8+i]);
    red[d][ec] = m8;
    __syncthreads();
    if (tid < 16){
        float m = red[tid][0];
        for (int j=1;j<16;j++) m = fmaxf(m, red[tid][j]);
        rowmax[tid] = m;
    }
    __syncthreads();
    const float rm = rowmax[d];
    float s8 = 0.f;
#pragma unroll
    for (int i=0;i<8;i++){
        float ex = expf(Es[d][ec*8+i] - rm);
        Es[d][ec*8+i] = ex;
        s8 += ex;
    }
    red[d][ec] = s8;
    __syncthreads();
    if (tid < 16){
        float sm = 0.f;
        for (int j=0;j<16;j++) sm += red[tid][j];
        rowsum[tid] = sm;
    }
    __syncthreads();
    const float inv = 1.f / rowsum[d];
    float ta = 0.f;
#pragma unroll
    for (int i=0;i<8;i++){
        const int e = ec*8 + i;
        float av = Es[d][e] * inv;
        Es[d][e] = av;
        ta += av * bv[e];
    }
    red[d][ec] = ta;
    __syncthreads();
    if (tid < 16){
        float sm = 0.f;
        for (int j=0;j<16;j++) sm += red[tid][j];
        tvec[b*NC + d0 + tid] = sm;
    }
    const int c0 = ec*8;
    float racc[8];
#pragma unroll
    for (int i=0;i<8;i++) racc[i]=0.f;
    for (int e=0;e<NC;e++){
        const float av = Es[d][e];
        const float* wv = Wv + (size_t)e*NC + c0;
        f32x4 w0 = *(const f32x4*)wv;
        f32x4 w1 = *(const f32x4*)(wv+4);
        racc[0]+=av*w0[0]; racc[1]+=av*w0[1]; racc[2]+=av*w0[2]; racc[3]+=av*w0[3];
        racc[4]+=av*w1[0]; racc[5]+=av*w1[1]; racc[6]+=av*w1[2]; racc[7]+=av*w1[3];
    }
    float* Rrow = R + ((size_t)b*NC + d0 + d)*NC + c0;
#pragma unroll
    for (int i=0;i<8;i++) Rrow[i] = racc[i];
}

// ---- K3: M' = gamma*Wo*R + I -> hi/lo bf16 B-fragments; cvg = gamma*(Wo t + bo) ----
// (round-12 verbatim, PASSING)
__global__ __launch_bounds__(256) void k_om(const float* __restrict__ R,
        const float* __restrict__ Wo, const float* __restrict__ bo,
        const float* __restrict__ tvec, const float* __restrict__ gamma,
        short* __restrict__ Mh_, short* __restrict__ Ml_, float* __restrict__ cvg){
    const int b = blockIdx.y, o0 = blockIdx.x*16;
    const int tid = threadIdx.x, o = tid&15, cc = tid>>4;
    const int c0 = cc*8;                      // cin octet base
    const float* Worow = Wo + (size_t)(o0+o)*NC;
    const float* tb = tvec + b*NC;
    float a[8];
#pragma unroll
    for (int i=0;i<8;i++) a[i]=0.f;
    float cv = 0.f;
    for (int dd=0; dd<NC; dd++){
        const float wv = Worow[dd];
        const float* r = R + ((size_t)b*NC + dd)*NC + c0;
        f32x4 r0 = *(const f32x4*)r;
        f32x4 r1 = *(const f32x4*)(r+4);
        a[0]+=wv*r0[0]; a[1]+=wv*r0[1]; a[2]+=wv*r0[2]; a[3]+=wv*r0[3];
        a[4]+=wv*r1[0]; a[5]+=wv*r1[1]; a[6]+=wv*r1[2]; a[7]+=wv*r1[3];
        cv += wv*tb[dd];
    }
    const float gm = gamma[0];
    const int c   = o0 + o;
    const int cg  = c >> 4;
    const int kst = cc >> 2, lgv = cc & 3;
    const size_t idx = ((((size_t)b*8 + cg)*4 + kst)*64 + (lgv*16 + (c & 15)))*8;
    short8 hh, ll;
#pragma unroll
    for (int i=0;i<8;i++){
        float val = gm*a[i] + ((c0 + i) == c ? 1.f : 0.f);   // M' = gm*M + I
        short hb, lb; cv2(val, hb, lb);
        hh[i]=hb; ll[i]=lb;
    }
    *(short8*)(Mh_ + idx) = hh;
    *(short8*)(Ml_ + idx) = ll;
    if (cc == 0) cvg[b*NC + c] = gm*(cv + bo[c]);
}

// ---- K4: out = M' x + cvg  (A = x from swizzled Xt; B = M' hi/lo) ----
// (round-12 verbatim, PASSING)
__global__ __launch_bounds__(256, 4) void k_final(const float* __restrict__ x,
        const short* __restrict__ Mh_, const short* __restrict__ Ml_,
        const float* __restrict__ cvg, float* __restrict__ out){
    __shared__ short Xt[NC*128];   // 32 KB: row n (local), 16 slots of 8 shorts
    const int b   = blockIdx.y;
    const int n0  = blockIdx.x * 128;
    const int tid = threadIdx.x;
    const int wid = tid >> 6, lane = tid & 63;
    const int l16 = lane & 15, lgi = lane >> 4;

    // ---- stage: thread (nr = tid&31, mb8 = tid>>5), 2 reps
    const int nr = tid & 31, mb8 = tid >> 5;
    const float* xs = x + (size_t)b*NC*NHW + n0 + nr*4;
#pragma unroll
    for (int rep=0; rep<2; rep++){
        const int m0 = rep*64 + mb8*8;
        const float* xm = xs + (size_t)m0*NHW;
        f32x4 v0 = *(const f32x4*)(xm);
        f32x4 v1 = *(const f32x4*)(xm + (size_t)1*NHW);
        f32x4 v2 = *(const f32x4*)(xm + (size_t)2*NHW);
        f32x4 v3 = *(const f32x4*)(xm + (size_t)3*NHW);
        f32x4 v4 = *(const f32x4*)(xm + (size_t)4*NHW);
        f32x4 v5 = *(const f32x4*)(xm + (size_t)5*NHW);
        f32x4 v6 = *(const f32x4*)(xm + (size_t)6*NHW);
        f32x4 v7 = *(const f32x4*)(xm + (size_t)7*NHW);
#pragma unroll
        for (int r=0;r<4;r++){
            short8 w;
            w[0]=bfbits(v0[r]); w[1]=bfbits(v1[r]); w[2]=bfbits(v2[r]); w[3]=bfbits(v3[r]);
            w[4]=bfbits(v4[r]); w[5]=bfbits(v5[r]); w[6]=bfbits(v6[r]); w[7]=bfbits(v7[r]);
            const int n = nr*4 + r;
            const int slot = (rep*8 + mb8) ^ ((n>>2)&15) ^ ((n&3)<<2);
            *(short8*)(&Xt[n*128 + slot*8]) = w;
        }
    }
    __syncthreads();

    f32x4 acc[2][8];   // [n 16-block t][cg]
#pragma unroll
    for (int t=0;t<2;t++)
#pragma unroll
      for (int g=0;g<8;g++) acc[t][g]=zero4();

    const short* Mh = Mh_ + (size_t)b*16384;
    const short* Ml = Ml_ + (size_t)b*16384;

#pragma unroll
    for (int ks=0; ks<4; ks++){
        const int nA0 = wid*32 + l16;
        const int nA1 = nA0 + 16;
        const int sl  = ks*4 + lgi;
        const int s0  = sl ^ ((nA0>>2)&15) ^ ((nA0&3)<<2);
        const int s1  = sl ^ ((nA1>>2)&15) ^ ((nA1&3)<<2);
        short8 a0 = *(const short8*)(&Xt[nA0*128 + s0*8]);
        short8 a1 = *(const short8*)(&Xt[nA1*128 + s1*8]);
#pragma unroll
        for (int cg=0; cg<8; cg++){
            const size_t bi = (((size_t)cg*4 + ks)*64 + lane)*8;
            short8 bh = *(const short8*)(Mh + bi);
            short8 bl = *(const short8*)(Ml + bi);
            acc[0][cg] = __builtin_amdgcn_mfma_f32_16x16x32_bf16(a0, bh, acc[0][cg], 0,0,0);
            acc[0][cg] = __builtin_amdgcn_mfma_f32_16x16x32_bf16(a0, bl, acc[0][cg], 0,0,0);
            acc[1][cg] = __builtin_amdgcn_mfma_f32_16x16x32_bf16(a1, bh, acc[1][cg], 0,0,0);
            acc[1][cg] = __builtin_amdgcn_mfma_f32_16x16x32_bf16(a1, bl, acc[1][cg], 0,0,0);
        }
    }

    // C/D: row(i)=n-offset=(lane>>4)*4+r, col(j)=c=cg*16+(lane&15)
    const float* cb = cvg + b*NC;
#pragma unroll
    for (int cg=0;cg<8;cg++){
        const int c = cg*16 + l16;
        const float ccv = cb[c];
        float* orow = &out[((size_t)b*NC + c)*NHW + n0 + wid*32 + lgi*4];
#pragma unroll
        for (int t=0;t<2;t++){
            f32x4 o = acc[t][cg];
            o[0]+=ccv; o[1]+=ccv; o[2]+=ccv; o[3]+=ccv;
            *(f32x4*)(orow + t*16) = o;
        }
    }
}

extern "C" void kernel_launch(void* const* d_in, const int* in_sizes, int n_in,
                              void* d_out, int out_size, void* d_ws, size_t ws_size,
                              hipStream_t stream){
    const float* x     = (const float*)d_in[0];
    const float* Wq    = (const float*)d_in[1];
    const float* bq    = (const float*)d_in[2];
    const float* Wk    = (const float*)d_in[3];
    const float* bk    = (const float*)d_in[4];
    const float* Wv    = (const float*)d_in[5];
    const float* bv    = (const float*)d_in[6];
    const float* Wo    = (const float*)d_in[7];
    const float* bo    = (const float*)d_in[8];
    const float* gamma = (const float*)d_in[9];
    float* out = (float*)d_out;

    float* w  = (float*)d_ws;
    float* G  = w + GOFF;
    float* S  = w + SOFF;
    float* T  = w + TOFF;
    float* R  = w + ROFF;
    float* CV = w + CVOFF;
    short* Mh = (short*)(w + MHOFF);
    short* Ml = (short*)(w + MLOFF);

    // zero atomic-accumulation targets (G: 131072 + svec: 1024 floats)
    k_zero    <<<dim3(129),     256, 0, stream>>>(G);

    k_gram    <<<dim3(32,  NB), 512, 0, stream>>>(x, G, S);
    k_energyav<<<dim3(8,   NB), 256, 0, stream>>>(G, S, Wq, bq, Wk, bk, bv, Wv, R, T);
    k_om      <<<dim3(8,   NB), 256, 0, stream>>>(R, Wo, bo, T, gamma, Mh, Ml, CV);
    k_final   <<<dim3(288, NB), 256, 0, stream>>>(x, Mh, Ml, CV, out);
}